// Round 3
// baseline (6739.433 us; speedup 1.0000x reference)
//
#include <hip/hip_runtime.h>
#include <hip/hip_bf16.h>
#include <stdint.h>

// BertBiLstmCrf: B=64 T=512 H=768 LH=384 L=12
// All tensors f32 on device (reference dtype). MFMA paths convert f32->bf16
// at LDS staging; accumulate f32. 8 phases of 64 steps keep ws at ~78 MB:
//   prep -> [gemm_xp(p) -> lstm_rec(p)] x8 -> fc_em -> viterbi
// lstm_rec: persistent 48 WG (24/dir), device-scope flag barrier per step,
// W_hh slice resident in LDS. out = f32 [score(64) | path(64*512)].

#define NB 64
#define NT 512
#define NH 768
#define NLH 384
#define NPH 8
#define PS 64            // steps per phase
#define NEGV -1000.0f

typedef __attribute__((ext_vector_type(4))) float f32x4;
typedef __attribute__((ext_vector_type(8))) short bf16x8;
typedef unsigned short u16;
typedef unsigned int u32;

__device__ __forceinline__ u16 f2bf(float f) {
  __hip_bfloat16 h = __float2bfloat16(f);
  return *reinterpret_cast<u16*>(&h);
}
__device__ __forceinline__ float bf2f(u16 u) {
  union { u32 i; float f; } v; v.i = ((u32)u) << 16; return v.f;
}
__device__ __forceinline__ u32 pack2(float a, float b) {
  return (u32)f2bf(a) | ((u32)f2bf(b) << 16);
}
__device__ __forceinline__ float sigm(float x) {
  x = fminf(fmaxf(x, -60.f), 60.f);
  return 1.0f / (1.0f + __expf(-x));
}
__device__ __forceinline__ float tanh_(float x) {
  x = fminf(fmaxf(x, -30.f), 30.f);
  return 2.0f / (1.0f + __expf(-2.0f * x)) - 1.0f;
}

// ---- prep: bias2=f32 sum, h0->bf16 hbuf slot0, c0->f32 cbuf, zero ctrs ------
__global__ __launch_bounds__(256) void prep_kernel(
    const float* bihf, const float* bhhf, const float* bihb, const float* bhhb,
    const float* h0, const float* c0, float* bias2, u16* hbuf, float* cbuf,
    u32* ctr) {
  int t = blockIdx.x * 256 + threadIdx.x;
  if (t < 1536) bias2[t] = bihf[t] + bhhf[t];
  else if (t < 3072) bias2[t] = bihb[t - 1536] + bhhb[t - 1536];
  if (t < 16) ctr[t] = 0;
  if (t < 2 * NB * NLH) {
    hbuf[t] = f2bf(h0[t]);      // slot p=0: [dir][b][j]
    cbuf[t] = c0[t];
  }
}

// ---- gemm_xp: XPc[(s*64+b)*3072 + n] = X[b, t(s,dir)] @ Wih^T + bias --------
// phase p: forward t = 64p + s ; backward t = 511 - 64p - s,  s in [0,64)
__global__ __launch_bounds__(256) void gemm_xp(
    const float* __restrict__ A, const float* __restrict__ Wf,
    const float* __restrict__ Wb, const float* __restrict__ bias2,
    u16* __restrict__ XPc, int phase) {
  __shared__ __align__(16) u16 As[128][40];  // bf16 tile, 80B row stride
  __shared__ __align__(16) u16 Bs[128][40];
  int nb = blockIdx.x;        // 0..23  (N=3072 in 128 cols)
  int mb = blockIdx.y;        // 0..31  (M=4096 in 128 rows)
  int dir = (nb >= 12) ? 1 : 0;
  const float* Bm = dir ? Wb : Wf;
  int n0g = nb * 128;
  int n0 = n0g - dir * 1536;
  int m0 = mb * 128;
  int tf0 = PS * phase, tb0 = (NT - 1) - PS * phase;
  int tid = threadIdx.x;
  int lane = tid & 63, wv = tid >> 6;
  int wm = (wv >> 1) * 64, wn = (wv & 1) * 64;
  int qr = lane & 15, qk8 = (lane >> 4) * 8, qm = (lane >> 4) * 4;

  f32x4 acc[4][4] = {};
  for (int kk = 0; kk < 768; kk += 32) {
    __syncthreads();
#pragma unroll
    for (int u = 0; u < 4; ++u) {
      int c = tid + u * 256;          // 1024 chunks of 4 f32 per tile
      int row = c >> 3, q4 = (c & 7) * 4;
      int m = m0 + row;
      int sloc = m >> 6, b = m & 63;
      int t = dir ? (tb0 - sloc) : (tf0 + sloc);
      float4 av = *(const float4*)&A[(size_t)(b * NT + t) * 768 + kk + q4];
      float4 bv = *(const float4*)&Bm[(size_t)(n0 + row) * 768 + kk + q4];
      uint2 ap; ap.x = pack2(av.x, av.y); ap.y = pack2(av.z, av.w);
      uint2 bp; bp.x = pack2(bv.x, bv.y); bp.y = pack2(bv.z, bv.w);
      *(uint2*)&As[row][q4] = ap;
      *(uint2*)&Bs[row][q4] = bp;
    }
    __syncthreads();
    bf16x8 af[4], bfr[4];
#pragma unroll
    for (int i = 0; i < 4; ++i) af[i] = *(const bf16x8*)&As[wm + i * 16 + qr][qk8];
#pragma unroll
    for (int j = 0; j < 4; ++j) bfr[j] = *(const bf16x8*)&Bs[wn + j * 16 + qr][qk8];
#pragma unroll
    for (int i = 0; i < 4; ++i)
#pragma unroll
      for (int j = 0; j < 4; ++j)
        acc[i][j] = __builtin_amdgcn_mfma_f32_16x16x32_bf16(af[i], bfr[j], acc[i][j], 0, 0, 0);
  }
#pragma unroll
  for (int j = 0; j < 4; ++j) {
    int n = n0g + wn + j * 16 + qr;
    float bv = bias2[n];
#pragma unroll
    for (int i = 0; i < 4; ++i)
#pragma unroll
      for (int r = 0; r < 4; ++r) {
        int m = m0 + wm + i * 16 + qm + r;     // m = s*64 + b
        XPc[(size_t)m * 3072 + n] = f2bf(acc[i][j][r] + bv);
      }
  }
}

// ---- lstm_rec: persistent, 24 WG/dir, flag barrier per step, 64 steps -------
__global__ __launch_bounds__(256) void lstm_rec(
    const float* __restrict__ Whhf, const float* __restrict__ Whhb,
    const u16* __restrict__ XPc, u16* hbuf, float* cbuf,
    u16* __restrict__ LOUT, u32* ctr, int phase) {
  const int G = 24;
  __shared__ __align__(16) u16 Ws[64][392];   // W_hh slice (bf16), resident
  __shared__ __align__(16) u16 hsm[64][392];  // h_{t-1} staged per step
  __shared__ __align__(16) float gb[64][68];  // gate exchange
  int wg = blockIdx.x;
  int dir = wg / G;
  int gidx = wg % G;
  int j0 = gidx * 16;
  int tid = threadIdx.x;
  int lane = tid & 63, wv = tid >> 6;
  int wm2 = (wv >> 1) * 32, wn2 = (wv & 1) * 32;
  int qr = lane & 15, qk8 = (lane >> 4) * 8, qm = (lane >> 4) * 4;
  const float* Whh = dir ? Whhb : Whhf;
  int tf0 = PS * phase, tb0 = (NT - 1) - PS * phase;
  u32* mc = &ctr[phase * 2 + dir];

  for (int c = tid; c < 6144; c += 256) {     // 64 Whh rows {g*384 + j0 + jj}
    int row = c / 96, q4 = (c % 96) * 4;      // 96 4-float chunks per row
    int g = row >> 4, jj = row & 15;
    float4 wv4 = *(const float4*)&Whh[(size_t)(g * 384 + j0 + jj) * 384 + q4];
    uint2 wp; wp.x = pack2(wv4.x, wv4.y); wp.y = pack2(wv4.z, wv4.w);
    *(uint2*)&Ws[row][q4] = wp;
  }
  int cb = tid >> 2, jq = (tid & 3) * 4;      // combine ownership: (batch, 4 j)
  float cst[4];
#pragma unroll
  for (int q = 0; q < 4; ++q)
    cst[q] = cbuf[(size_t)dir * NB * NLH + cb * NLH + j0 + jq + q];

  u32 target = 0;
  for (int s = 0; s < PS; ++s) {
    int t = dir ? (tb0 - s) : (tf0 + s);
    int pp = s & 1;
    const u16* hsrc = hbuf + ((size_t)(pp * 2 + dir)) * NB * NLH;
    u16* hdst = hbuf + ((size_t)((pp ^ 1) * 2 + dir)) * NB * NLH;
    for (int c = tid; c < 3072; c += 256) {   // stage h_{t-1} (bf16)
      int row = c / 48, seg = c % 48;
      *(uint4*)&hsm[row][seg * 8] = *(const uint4*)&hsrc[(size_t)row * 384 + seg * 8];
    }
    __syncthreads();
    f32x4 acc[2][2] = {};                     // gates(64b x 64) = h @ Ws^T
#pragma unroll
    for (int kk = 0; kk < 12; ++kk) {
      bf16x8 af[2], bfr[2];
#pragma unroll
      for (int i = 0; i < 2; ++i) af[i] = *(const bf16x8*)&hsm[wm2 + i * 16 + qr][kk * 32 + qk8];
#pragma unroll
      for (int j = 0; j < 2; ++j) bfr[j] = *(const bf16x8*)&Ws[wn2 + j * 16 + qr][kk * 32 + qk8];
#pragma unroll
      for (int i = 0; i < 2; ++i)
#pragma unroll
        for (int j = 0; j < 2; ++j)
          acc[i][j] = __builtin_amdgcn_mfma_f32_16x16x32_bf16(af[i], bfr[j], acc[i][j], 0, 0, 0);
    }
#pragma unroll
    for (int i = 0; i < 2; ++i)
#pragma unroll
      for (int j = 0; j < 2; ++j)
#pragma unroll
        for (int r = 0; r < 4; ++r)
          gb[wm2 + i * 16 + qm + r][wn2 + j * 16 + qr] = acc[i][j][r];
    __syncthreads();
    // combine i,f,g,o -> c,h
    const u16* xpb = XPc + ((size_t)s * 64 + cb) * 3072 + dir * 1536;
    float pre[4][4];
#pragma unroll
    for (int g = 0; g < 4; ++g) {
      f32x4 gv = *(const f32x4*)&gb[cb][g * 16 + jq];
      uint2 xv = *(const uint2*)&xpb[g * 384 + j0 + jq];
      pre[g][0] = gv[0] + bf2f((u16)(xv.x & 0xffff));
      pre[g][1] = gv[1] + bf2f((u16)(xv.x >> 16));
      pre[g][2] = gv[2] + bf2f((u16)(xv.y & 0xffff));
      pre[g][3] = gv[3] + bf2f((u16)(xv.y >> 16));
    }
    u32 pk0 = 0, pk1 = 0;
#pragma unroll
    for (int q = 0; q < 4; ++q) {
      float ig = sigm(pre[0][q]);
      float fg = sigm(pre[1][q]);
      float gg = tanh_(pre[2][q]);
      float og = sigm(pre[3][q]);
      float cv = fg * cst[q] + ig * gg;
      cst[q] = cv;
      u32 hb = f2bf(og * tanh_(cv));
      if (q == 0) pk0 = hb;
      else if (q == 1) pk0 |= hb << 16;
      else if (q == 2) pk1 = hb;
      else pk1 |= hb << 16;
    }
    uint2 pk; pk.x = pk0; pk.y = pk1;
    *(uint2*)&hdst[(size_t)cb * NLH + j0 + jq] = pk;
    *(uint2*)&LOUT[((size_t)cb * NT + t) * 768 + dir * 384 + j0 + jq] = pk;
    // device barrier among the G WGs of this direction
    __syncthreads();  // drains vmcnt before s_barrier (release of h stores)
    target += G;
    if (tid == 0) {
      __hip_atomic_fetch_add(mc, 1u, __ATOMIC_RELEASE, __HIP_MEMORY_SCOPE_AGENT);
      int spins = 0;
      while (__hip_atomic_load(mc, __ATOMIC_RELAXED, __HIP_MEMORY_SCOPE_AGENT) < target) {
        __builtin_amdgcn_s_sleep(1);
        if (++spins > (1 << 20)) break;  // liveness guard
      }
    }
    __syncthreads();
    __threadfence();  // device-scope acquire for ALL threads before h reload
  }
  // persist c state for next phase
#pragma unroll
  for (int q = 0; q < 4; ++q)
    cbuf[(size_t)dir * NB * NLH + cb * NLH + j0 + jq + q] = cst[q];
}

// ---- fc_em: emissions = LOUT @ fc_w^T + fc_b --------------------------------
__global__ __launch_bounds__(256) void fc_em(
    const u16* __restrict__ LOUT, const float* __restrict__ fcw,
    const float* __restrict__ fcb, float* __restrict__ em) {
  __shared__ float wsm[12][768];
  __shared__ float wbv[12];
  int tid = threadIdx.x;
  for (int i = tid; i < 12 * 768; i += 256) wsm[i / 768][i % 768] = fcw[i];
  if (tid < 12) wbv[tid] = fcb[tid];
  __syncthreads();
  int lane = tid & 63, wv = tid >> 6;
  for (int r = blockIdx.x * 4 + wv; r < NB * NT; r += gridDim.x * 4) {
    float x[12];
#pragma unroll
    for (int c = 0; c < 12; ++c) x[c] = bf2f(LOUT[(size_t)r * 768 + c * 64 + lane]);
    float sums[12];
#pragma unroll
    for (int l = 0; l < 12; ++l) {
      float pv = 0.f;
#pragma unroll
      for (int c = 0; c < 12; ++c) pv += x[c] * wsm[l][c * 64 + lane];
#pragma unroll
      for (int off = 32; off > 0; off >>= 1) pv += __shfl_xor(pv, off);
      sums[l] = pv + wbv[l];
    }
    if (lane == 0) {
#pragma unroll
      for (int l = 0; l < 12; ++l) em[(size_t)r * 12 + l] = sums[l];
    }
  }
}

// ---- viterbi: one wave per batch --------------------------------------------
__global__ __launch_bounds__(256) void viterbi_k(
    const float* __restrict__ em, const float* __restrict__ trans,
    const int* __restrict__ startp, unsigned char* __restrict__ ptrs,
    float* __restrict__ outp) {
  int tid = threadIdx.x;
  int lane = tid & 63, wv = tid >> 6;
  int b = blockIdx.x * 4 + wv;
  int l = lane;
  int start = startp[0];
  float tr[12];
#pragma unroll
  for (int p = 0; p < 12; ++p) tr[p] = (l < 12) ? trans[l * 12 + p] : NEGV;
  float fv = (l == start) ? 0.f : NEGV;  // lanes >=12 stay NEG forever
  for (int t = 1; t < NT; ++t) {
    float feat = (l < 12) ? em[((size_t)b * NT + t) * 12 + l] : 0.f;
    float best = -3.4e38f; int bp = 0;
#pragma unroll
    for (int p = 0; p < 12; ++p) {
      float v = __shfl(fv, p) + tr[p];
      if (v > best) { best = v; bp = p; }  // strict > = first-index argmax
    }
    if (l < 12) {
      fv = best + feat;
      ptrs[((size_t)b * (NT - 1) + (t - 1)) * 12 + l] = (unsigned char)bp;
    }
  }
  float bv = fv; int bi = l;
#pragma unroll
  for (int off = 32; off > 0; off >>= 1) {
    float v2 = __shfl_xor(bv, off); int i2 = __shfl_xor(bi, off);
    if (v2 > bv || (v2 == bv && i2 < bi)) { bv = v2; bi = i2; }
  }
  int nxt = bi;
  if (lane == 0) {
    outp[b] = bv;
    outp[64 + (size_t)b * NT + (NT - 1)] = (float)nxt;
  }
  int pb = (l < 12) ? (int)ptrs[((size_t)b * (NT - 1) + (NT - 2)) * 12 + l] : 0;
  for (int t = NT - 2; t >= 0; --t) {
    int pbn = (t > 0) ? ((l < 12) ? (int)ptrs[((size_t)b * (NT - 1) + (t - 1)) * 12 + l] : 0) : 0;
    nxt = __shfl(pb, nxt);
    if (lane == 0) outp[64 + (size_t)b * NT + t] = (float)nxt;
    pb = pbn;
  }
}

// ---- launch -----------------------------------------------------------------
extern "C" void kernel_launch(void* const* d_in, const int* in_sizes, int n_in,
                              void* d_out, int out_size, void* d_ws, size_t ws_size,
                              hipStream_t stream) {
  const float* X     = (const float*)d_in[0];
  const float* h0    = (const float*)d_in[1];
  const float* c0    = (const float*)d_in[2];
  const float* wihf  = (const float*)d_in[3];
  const float* whhf  = (const float*)d_in[4];
  const float* bihf  = (const float*)d_in[5];
  const float* bhhf  = (const float*)d_in[6];
  const float* wihb  = (const float*)d_in[7];
  const float* whhb  = (const float*)d_in[8];
  const float* bihb  = (const float*)d_in[9];
  const float* bhhb  = (const float*)d_in[10];
  const float* fcw   = (const float*)d_in[11];
  const float* fcb   = (const float*)d_in[12];
  const float* trans = (const float*)d_in[13];
  const int* startp  = (const int*)d_in[14];
  float* outp = (float*)d_out;
  char* ws = (char*)d_ws;

  // workspace layout (total ~77.9 MB)
  float* bias2 = (float*)(ws + 0);                       //     12,288
  u16* hbuf    = (u16*)(ws + 12288);                     //    196,608
  float* cbuf  = (float*)(ws + 208896);                  //    196,608
  u32* ctr     = (u32*)(ws + 405504);                    //       1024
  u16* XPc     = (u16*)(ws + 406528);                    // 25,165,824
  u16* LOUT    = (u16*)(ws + 25572352);                  // 50,331,648
  float* em    = (float*)(ws + 75904000);                //  1,572,864
  unsigned char* ptrs = (unsigned char*)(ws + 77476864); //    392,448

  prep_kernel<<<192, 256, 0, stream>>>(bihf, bhhf, bihb, bhhb, h0, c0,
                                       bias2, hbuf, cbuf, ctr);
  for (int p = 0; p < NPH; ++p) {
    gemm_xp<<<dim3(24, 32), 256, 0, stream>>>(X, wihf, wihb, bias2, XPc, p);
    lstm_rec<<<48, 256, 0, stream>>>(whhf, whhb, XPc, hbuf, cbuf, LOUT, ctr, p);
  }
  fc_em<<<128, 256, 0, stream>>>(LOUT, fcw, fcb, em);
  viterbi_k<<<16, 256, 0, stream>>>(em, trans, startp, ptrs, outp);
}